// Round 5
// baseline (247.620 us; speedup 1.0000x reference)
//
#include <hip/hip_runtime.h>
#include <hip/hip_bf16.h>
#include <math.h>

#define NN 20000
#define EE 640000

typedef __attribute__((ext_vector_type(8))) short short8;
typedef __attribute__((ext_vector_type(4))) float f32x4;
typedef __hip_bfloat16 bf16;

__device__ inline ushort f2bf(float f) {
  bf16 h = __float2bfloat16(f);
  return *(ushort*)&h;
}
__device__ inline float bflo(uint u) { return __uint_as_float(u << 16); }
__device__ inline float bfhi(uint u) { return __uint_as_float(u & 0xFFFF0000u); }

// ---------------------------------------------------------------------------
// Kernel 1: prep + scatter fused.
//  b <  2500      : edge scatter (atomic cursor, 128 slots/node; Poisson(32),
//                   P(deg>128) ~ 1e-30)
//  b < 3750       : xb = bf16(x)
//  b = 3750..3752 : Wt{q,k,v}[n][k] = bf16(W[k][n])   (two col-halves)
//  b = 3753..3754 : Wot[n][256] from Wo[256][128]
//  b = 3755       : Wvpsi fused weight + bvpsi bias (psi folded into QKV GEMM)
// ---------------------------------------------------------------------------
__global__ __launch_bounds__(256) void prep_scatter(
    const float* __restrict__ x, const int* __restrict__ ei,
    const float* __restrict__ Wq, const float* __restrict__ Wk,
    const float* __restrict__ Wv, const float* __restrict__ Wo,
    const float* __restrict__ Wpsi, const float* __restrict__ bpsi,
    const float* __restrict__ bv,
    ushort* __restrict__ xb, ushort* __restrict__ Wts,
    ushort* __restrict__ Wot, float* __restrict__ bvpsi,
    int* __restrict__ cursor, int* __restrict__ scol) {
  __shared__ float T[128][65];
  __shared__ float WpsiS[256];
  __shared__ float bpsiS[16];
  int b = blockIdx.x, t = threadIdx.x;

  if (b < 2500) {  // edge scatter
    int e = b * 256 + t;
    int r = ei[e];
    int c = ei[EE + e];
    int pos = atomicAdd(&cursor[r], 1);
    if (pos < 128) scol[r * 128 + pos] = c;
    return;
  }
  if (b < 3750) {  // x -> bf16
    int idx = (b - 2500) * 2048 + t * 8;
    float4 f0 = *(const float4*)(x + idx);
    float4 f1 = *(const float4*)(x + idx + 4);
    ushort tmp[8] = {f2bf(f0.x), f2bf(f0.y), f2bf(f0.z), f2bf(f0.w),
                     f2bf(f1.x), f2bf(f1.y), f2bf(f1.z), f2bf(f1.w)};
    *(uint4*)(xb + idx) = *(uint4*)tmp;
    return;
  }
  if (b <= 3754) {  // weight transposes, two column-halves
    int which = b - 3750;
    const float* W;
    int k0 = 0, dstride;
    ushort* dst;
    if (which < 3) { W = (which == 0) ? Wq : (which == 1 ? Wk : Wv);
                     dst = Wts + which * 16384; dstride = 128; }
    else { W = Wo; k0 = (which - 3) * 128; dst = Wot; dstride = 256; }
    for (int h2 = 0; h2 < 2; ++h2) {
      int r = t >> 1, c0 = (t & 1) * 32;
      const float* src = W + (size_t)(k0 + r) * 128 + h2 * 64 + c0;
#pragma unroll
      for (int j = 0; j < 8; ++j) {
        float4 f = *(const float4*)(src + 4 * j);
        T[r][c0 + 4 * j + 0] = f.x; T[r][c0 + 4 * j + 1] = f.y;
        T[r][c0 + 4 * j + 2] = f.z; T[r][c0 + 4 * j + 3] = f.w;
      }
      __syncthreads();
      int nl = t >> 2, kc = (t & 3) * 32;
      int n = h2 * 64 + nl;
      ushort buf[32];
#pragma unroll
      for (int k = 0; k < 32; ++k) buf[k] = f2bf(T[kc + k][nl]);
      ushort* dp = dst + (size_t)n * dstride + k0 + kc;
#pragma unroll
      for (int j = 0; j < 4; ++j) *(uint4*)(dp + 8 * j) = ((uint4*)buf)[j];
      __syncthreads();
    }
    return;
  }
  // b == 3755: Wvpsi[n][k] = sum_dp Wv[k][h*16+dp]*Wpsi[dp][d]  (n = h*16+d)
  WpsiS[t] = Wpsi[t];
  if (t < 16) bpsiS[t] = bpsi[t];
  for (int h2 = 0; h2 < 2; ++h2) {
    int r = t >> 1, c0 = (t & 1) * 32;
    const float* src = Wv + (size_t)r * 128 + h2 * 64 + c0;
#pragma unroll
    for (int j = 0; j < 8; ++j) {
      float4 f = *(const float4*)(src + 4 * j);
      T[r][c0 + 4 * j + 0] = f.x; T[r][c0 + 4 * j + 1] = f.y;
      T[r][c0 + 4 * j + 2] = f.z; T[r][c0 + 4 * j + 3] = f.w;
    }
    __syncthreads();
    int nl = t >> 2, kc = (t & 3) * 32;
    int n = h2 * 64 + nl;
    int hh = n >> 4, dd = n & 15;
    int lcb = hh * 16 - h2 * 64;  // psi-input cols within this half
    ushort buf[32];
    for (int k = 0; k < 32; ++k) {
      float acc = 0.f;
#pragma unroll
      for (int dp = 0; dp < 16; ++dp)
        acc = fmaf(T[kc + k][lcb + dp], WpsiS[dp * 16 + dd], acc);
      buf[k] = f2bf(acc);
    }
    ushort* dp2 = Wts + 3 * 16384 + (size_t)n * 128 + kc;
#pragma unroll
    for (int j = 0; j < 4; ++j) *(uint4*)(dp2 + 8 * j) = ((uint4*)buf)[j];
    __syncthreads();
  }
  if (t < 128) {
    int hh = t >> 4, dd = t & 15;
    float acc = bpsiS[dd];
#pragma unroll
    for (int dp = 0; dp < 16; ++dp)
      acc = fmaf(bv[hh * 16 + dp], WpsiS[dp * 16 + dd], acc);
    bvpsi[t] = acc;
  }
}

// ---------------------------------------------------------------------------
// Kernel 2: QKV+Vpsi GEMM (LDS-free MFMA main loop, LDS-transposed epilogue
// for coalesced uint4 stores).  blockIdx.y = mat: 0:q  1:k  2:v  3:tanh(psi).
// All outputs bf16: q -> qb[N][128]; k/v/vb -> kvb[n][384] at 0/128/256.
// ---------------------------------------------------------------------------
__global__ __launch_bounds__(256) void qkv_mfma(
    const ushort* __restrict__ xb, const ushort* __restrict__ Wts,
    const float* __restrict__ bq, const float* __restrict__ bk,
    const float* __restrict__ bv, const float* __restrict__ bvpsi,
    ushort* __restrict__ qb, ushort* __restrict__ kvb) {
  __shared__ ushort Tile[128 * 136];
  int t = threadIdx.x;
  int w = t >> 6, lane = t & 63;
  int m = lane & 15, qd = lane >> 4;
  int n0 = blockIdx.x * 128;
  int mat = blockIdx.y;
  const ushort* Wt = Wts + mat * 16384;
  const float* bias = (mat == 0) ? bq : (mat == 1 ? bk : (mat == 2 ? bv : bvpsi));
  int gr0 = n0 + w * 32;

  f32x4 acc0[8], acc1[8];
#pragma unroll
  for (int c = 0; c < 8; ++c) {
    acc0[c] = (f32x4){0.f, 0.f, 0.f, 0.f};
    acc1[c] = (f32x4){0.f, 0.f, 0.f, 0.f};
  }
#pragma unroll
  for (int kb = 0; kb < 4; ++kb) {
    int ko = kb * 32 + qd * 8;
    short8 a0 = *(const short8*)(xb + (size_t)(gr0 + m) * 128 + ko);
    short8 a1 = *(const short8*)(xb + (size_t)(gr0 + 16 + m) * 128 + ko);
#pragma unroll
    for (int c = 0; c < 8; ++c) {
      short8 bfr = *(const short8*)(Wt + (size_t)(c * 16 + m) * 128 + ko);
      acc0[c] = __builtin_amdgcn_mfma_f32_16x16x32_bf16(a0, bfr, acc0[c], 0, 0, 0);
      acc1[c] = __builtin_amdgcn_mfma_f32_16x16x32_bf16(a1, bfr, acc1[c], 0, 0, 0);
    }
  }
  // bias + (tanh) + write to LDS tile
#pragma unroll
  for (int c = 0; c < 8; ++c) {
    int col = c * 16 + m;
    float bb = bias[col];
#pragma unroll
    for (int reg = 0; reg < 4; ++reg) {
      float v0 = acc0[c][reg] + bb;
      float v1 = acc1[c][reg] + bb;
      if (mat == 3) { v0 = tanhf(v0); v1 = tanhf(v1); }
      Tile[(w * 32 + 4 * qd + reg) * 136 + col] = f2bf(v0);
      Tile[(w * 32 + 16 + 4 * qd + reg) * 136 + col] = f2bf(v1);
    }
  }
  __syncthreads();
  // coalesced store: thread owns half a row (64 ushorts = 128 B)
  int row = t >> 1, half = (t & 1) * 64;
  int grow = n0 + row;
  if (grow < NN) {
    const ushort* srcl = &Tile[row * 136 + half];
    ushort* dstg;
    if (mat == 0) dstg = qb + (size_t)grow * 128 + half;
    else dstg = kvb + (size_t)grow * 384 + (mat == 1 ? 0 : (mat == 2 ? 128 : 256)) + half;
#pragma unroll
    for (int j = 0; j < 8; ++j)
      *(uint4*)(dstg + 8 * j) = *(const uint4*)(srcl + 8 * j);
  }
}

// ---------------------------------------------------------------------------
// Kernel 3: aggregate.  TWO waves per node (4 heads each); lane = e*4 + h4
// (e = 0..15 edge slots in flight, h4 = head within wave-half).  Each lane
// owns all 16 dims of its head: dot = 16 in-lane FMAs, zero per-edge shfl.
// End: xor-32 pre-round on all accs, then lanes e<8 reduce V / e>=8 reduce B
// over masks 4/8/16.  Output hb bf16 (feeds output MFMA).
// ---------------------------------------------------------------------------
__global__ __launch_bounds__(256) void aggregate_kernel(
    const ushort* __restrict__ qb, const ushort* __restrict__ kvb,
    const int* __restrict__ cursor, const int* __restrict__ scol,
    ushort* __restrict__ hb) {
  int wid = threadIdx.x >> 6, lane = threadIdx.x & 63;
  int node = blockIdx.x * 2 + (wid >> 1);
  int e = lane >> 2, h = (wid & 1) * 4 + (lane & 3);
  const float SC = 0.25f * 1.44269504f;  // 1/sqrt(D) * log2(e)

  float qv[16];
  {
    const ushort* qp = qb + (size_t)node * 128 + h * 16;
    uint4 a = *(const uint4*)qp;
    uint4 b = *(const uint4*)(qp + 8);
    uint qq[8] = {a.x, a.y, a.z, a.w, b.x, b.y, b.z, b.w};
#pragma unroll
    for (int i = 0; i < 8; ++i) {
      qv[2 * i] = bflo(qq[i]) * SC;
      qv[2 * i + 1] = bfhi(qq[i]) * SC;
    }
  }
  int cnt = cursor[node];
  cnt = cnt > 128 ? 128 : cnt;
  int base = node * 128;

  float s = 0.f;
  float accV[16], accB[16];
#pragma unroll
  for (int j = 0; j < 16; ++j) { accV[j] = 0.f; accB[j] = 0.f; }

  for (int i0 = 0; i0 < cnt; i0 += 16) {
    int idx = i0 + e;
    bool valid = idx < cnt;
    int col = scol[base + (valid ? idx : 0)];
    const ushort* B = kvb + (size_t)col * 384 + h * 16;
    uint4 ka = *(const uint4*)(B);
    uint4 kb4 = *(const uint4*)(B + 8);
    uint4 va = *(const uint4*)(B + 128);
    uint4 vb4 = *(const uint4*)(B + 136);
    uint4 ta = *(const uint4*)(B + 256);
    uint4 tb4 = *(const uint4*)(B + 264);
    uint kk[8] = {ka.x, ka.y, ka.z, ka.w, kb4.x, kb4.y, kb4.z, kb4.w};
    uint vv[8] = {va.x, va.y, va.z, va.w, vb4.x, vb4.y, vb4.z, vb4.w};
    uint tt[8] = {ta.x, ta.y, ta.z, ta.w, tb4.x, tb4.y, tb4.z, tb4.w};
    float d = 0.f;
#pragma unroll
    for (int i = 0; i < 8; ++i) {
      d = fmaf(qv[2 * i], bflo(kk[i]), d);
      d = fmaf(qv[2 * i + 1], bfhi(kk[i]), d);
    }
    float wgt = valid ? exp2f(d) : 0.f;
    s += wgt;
#pragma unroll
    for (int i = 0; i < 8; ++i) {
      accV[2 * i]     = fmaf(wgt, bflo(vv[i]), accV[2 * i]);
      accV[2 * i + 1] = fmaf(wgt, bfhi(vv[i]), accV[2 * i + 1]);
      accB[2 * i]     = fmaf(wgt, bflo(tt[i]), accB[2 * i]);
      accB[2 * i + 1] = fmaf(wgt, bfhi(tt[i]), accB[2 * i + 1]);
    }
  }

  // pre-round over e bit3 (lane bit 5) on everything
  s += __shfl_xor(s, 32);
#pragma unroll
  for (int j = 0; j < 16; ++j) {
    accV[j] += __shfl_xor(accV[j], 32);
    accB[j] += __shfl_xor(accB[j], 32);
  }
  // lanes e<8 finish V, e>=8 finish B
  bool pickV = e < 8;
  float sel[16];
#pragma unroll
  for (int j = 0; j < 16; ++j) sel[j] = pickV ? accV[j] : accB[j];
#pragma unroll
  for (int mask = 4; mask <= 16; mask <<= 1) {
    s += __shfl_xor(s, mask);
#pragma unroll
    for (int j = 0; j < 16; ++j) sel[j] += __shfl_xor(sel[j], mask);
  }
  float inv = s > 0.f ? 1.f / s : 0.f;
  int dg = pickV ? 2 * e : 2 * (e - 8);
  ushort* hp = hb + (size_t)node * 256 + (pickV ? 0 : 128) + h * 16 + dg;
  uint u = (uint)f2bf(sel[dg] * inv) | ((uint)f2bf(sel[dg + 1] * inv) << 16);
  *(uint*)hp = u;
}

// ---------------------------------------------------------------------------
// Kernel 4: out = LN(x + relu(hb @ Wo + bo)) * gamma + beta, LDS-free MFMA.
// 314 blocks x 128 threads (2 waves, 32 rows each) -> all CUs covered.
// ---------------------------------------------------------------------------
__global__ __launch_bounds__(128) void output_mfma(
    const ushort* __restrict__ hb, const ushort* __restrict__ Wot,
    const float* __restrict__ x, const float* __restrict__ bo,
    const float* __restrict__ gamma, const float* __restrict__ beta,
    float* __restrict__ out) {
  int t = threadIdx.x;
  int w = t >> 6, lane = t & 63;
  int m = lane & 15, qd = lane >> 4;
  int gr0 = blockIdx.x * 64 + w * 32;

  f32x4 acc0[8], acc1[8];
#pragma unroll
  for (int c = 0; c < 8; ++c) {
    acc0[c] = (f32x4){0.f, 0.f, 0.f, 0.f};
    acc1[c] = (f32x4){0.f, 0.f, 0.f, 0.f};
  }
#pragma unroll
  for (int kb = 0; kb < 8; ++kb) {
    int ko = kb * 32 + qd * 8;
    short8 a0 = *(const short8*)(hb + (size_t)(gr0 + m) * 256 + ko);
    short8 a1 = *(const short8*)(hb + (size_t)(gr0 + 16 + m) * 256 + ko);
#pragma unroll
    for (int c = 0; c < 8; ++c) {
      short8 bfr = *(const short8*)(Wot + (size_t)(c * 16 + m) * 256 + ko);
      acc0[c] = __builtin_amdgcn_mfma_f32_16x16x32_bf16(a0, bfr, acc0[c], 0, 0, 0);
      acc1[c] = __builtin_amdgcn_mfma_f32_16x16x32_bf16(a1, bfr, acc1[c], 0, 0, 0);
    }
  }
#pragma unroll
  for (int half = 0; half < 2; ++half) {
#pragma unroll
    for (int reg = 0; reg < 4; ++reg) {
      int row = gr0 + half * 16 + 4 * qd + reg;
      bool valid = row < NN;
      float vals[8];
      float sum = 0.f;
#pragma unroll
      for (int c = 0; c < 8; ++c) {
        int col = c * 16 + m;
        float a = (half ? acc1[c][reg] : acc0[c][reg]) + bo[col];
        a = fmaxf(a, 0.f);
        float xv = valid ? x[(size_t)row * 128 + col] : 0.f;
        float v = a + xv;
        vals[c] = v;
        sum += v;
      }
      sum += __shfl_xor(sum, 1); sum += __shfl_xor(sum, 2);
      sum += __shfl_xor(sum, 4); sum += __shfl_xor(sum, 8);
      float mean = sum * (1.f / 128.f);
      float ssq = 0.f;
#pragma unroll
      for (int c = 0; c < 8; ++c) {
        float d = vals[c] - mean;
        ssq = fmaf(d, d, ssq);
      }
      ssq += __shfl_xor(ssq, 1); ssq += __shfl_xor(ssq, 2);
      ssq += __shfl_xor(ssq, 4); ssq += __shfl_xor(ssq, 8);
      float rstd = rsqrtf(ssq * (1.f / 128.f) + 1e-5f);
      if (valid) {
#pragma unroll
        for (int c = 0; c < 8; ++c) {
          int col = c * 16 + m;
          out[(size_t)row * 128 + col] =
              (vals[c] - mean) * rstd * gamma[col] + beta[col];
        }
      }
    }
  }
}

// ---------------------------------------------------------------------------
extern "C" void kernel_launch(void* const* d_in, const int* in_sizes, int n_in,
                              void* d_out, int out_size, void* d_ws, size_t ws_size,
                              hipStream_t stream) {
  const float* x     = (const float*)d_in[0];
  const int*   ei    = (const int*)d_in[1];
  const float* Wq    = (const float*)d_in[2];
  const float* bq    = (const float*)d_in[3];
  const float* Wk    = (const float*)d_in[4];
  const float* bk    = (const float*)d_in[5];
  const float* Wv    = (const float*)d_in[6];
  const float* bv    = (const float*)d_in[7];
  const float* Wpsi  = (const float*)d_in[8];
  const float* bpsi  = (const float*)d_in[9];
  const float* Wo    = (const float*)d_in[10];
  const float* bo    = (const float*)d_in[11];
  const float* gamma = (const float*)d_in[12];
  const float* beta  = (const float*)d_in[13];
  float* out = (float*)d_out;

  char* ws = (char*)d_ws;
  ushort* xb    = (ushort*)(ws);                // 20096*128*2 = 5,144,576
  ushort* qb    = (ushort*)(ws + 5144576);      // 5,144,576
  ushort* Wts   = (ushort*)(ws + 10289152);     // 131,072
  ushort* Wot   = (ushort*)(ws + 10420224);     // 65,536
  float*  bvpsi = (float*) (ws + 10485760);     // 512
  ushort* kvb   = (ushort*)(ws + 10486272);     // 15,360,000
  ushort* hb    = (ushort*)(ws + 25846272);     // 20096*256*2 = 10,289,152
  int*    cursor= (int*)   (ws + 36135424);     // 80,000 (+pad)
  int*    scol  = (int*)   (ws + 36215552);     // 10,240,000  (total ~46.5 MB)

  hipMemsetAsync(cursor, 0, 80000, stream);

  prep_scatter<<<3756, 256, 0, stream>>>(x, ei, Wq, Wk, Wv, Wo, Wpsi, bpsi, bv,
                                         xb, Wts, Wot, bvpsi, cursor, scol);
  qkv_mfma<<<dim3(157, 4), 256, 0, stream>>>(xb, Wts, bq, bk, bv, bvpsi, qb, kvb);
  aggregate_kernel<<<10000, 256, 0, stream>>>(qb, kvb, cursor, scol, hb);
  output_mfma<<<314, 128, 0, stream>>>(hb, Wot, x, bo, gamma, beta, out);
}

// Round 6
// 242.255 us; speedup vs baseline: 1.0221x; 1.0221x over previous
//
#include <hip/hip_runtime.h>
#include <hip/hip_bf16.h>
#include <math.h>

#define NN 20000
#define EE 640000

typedef __attribute__((ext_vector_type(8))) short short8;
typedef __attribute__((ext_vector_type(4))) float f32x4;
typedef __hip_bfloat16 bf16;

__device__ inline ushort f2bf(float f) {
  bf16 h = __float2bfloat16(f);
  return *(ushort*)&h;
}
__device__ inline float bflo(uint u) { return __uint_as_float(u << 16); }
__device__ inline float bfhi(uint u) { return __uint_as_float(u & 0xFFFF0000u); }

// ---------------------------------------------------------------------------
// Kernel 1: prep + scatter fused (unchanged from R5).
// ---------------------------------------------------------------------------
__global__ __launch_bounds__(256) void prep_scatter(
    const float* __restrict__ x, const int* __restrict__ ei,
    const float* __restrict__ Wq, const float* __restrict__ Wk,
    const float* __restrict__ Wv, const float* __restrict__ Wo,
    const float* __restrict__ Wpsi, const float* __restrict__ bpsi,
    const float* __restrict__ bv,
    ushort* __restrict__ xb, ushort* __restrict__ Wts,
    ushort* __restrict__ Wot, float* __restrict__ bvpsi,
    int* __restrict__ cursor, int* __restrict__ scol) {
  __shared__ float T[128][65];
  __shared__ float WpsiS[256];
  __shared__ float bpsiS[16];
  int b = blockIdx.x, t = threadIdx.x;

  if (b < 2500) {  // edge scatter: 128 slots/node (Poisson(32), P(>128)~1e-30)
    int e = b * 256 + t;
    int r = ei[e];
    int c = ei[EE + e];
    int pos = atomicAdd(&cursor[r], 1);
    if (pos < 128) scol[r * 128 + pos] = c;
    return;
  }
  if (b < 3750) {  // x -> bf16
    int idx = (b - 2500) * 2048 + t * 8;
    float4 f0 = *(const float4*)(x + idx);
    float4 f1 = *(const float4*)(x + idx + 4);
    ushort tmp[8] = {f2bf(f0.x), f2bf(f0.y), f2bf(f0.z), f2bf(f0.w),
                     f2bf(f1.x), f2bf(f1.y), f2bf(f1.z), f2bf(f1.w)};
    *(uint4*)(xb + idx) = *(uint4*)tmp;
    return;
  }
  if (b <= 3754) {  // weight transposes
    int which = b - 3750;
    const float* W;
    int k0 = 0, dstride;
    ushort* dst;
    if (which < 3) { W = (which == 0) ? Wq : (which == 1 ? Wk : Wv);
                     dst = Wts + which * 16384; dstride = 128; }
    else { W = Wo; k0 = (which - 3) * 128; dst = Wot; dstride = 256; }
    for (int h2 = 0; h2 < 2; ++h2) {
      int r = t >> 1, c0 = (t & 1) * 32;
      const float* src = W + (size_t)(k0 + r) * 128 + h2 * 64 + c0;
#pragma unroll
      for (int j = 0; j < 8; ++j) {
        float4 f = *(const float4*)(src + 4 * j);
        T[r][c0 + 4 * j + 0] = f.x; T[r][c0 + 4 * j + 1] = f.y;
        T[r][c0 + 4 * j + 2] = f.z; T[r][c0 + 4 * j + 3] = f.w;
      }
      __syncthreads();
      int nl = t >> 2, kc = (t & 3) * 32;
      int n = h2 * 64 + nl;
      ushort buf[32];
#pragma unroll
      for (int k = 0; k < 32; ++k) buf[k] = f2bf(T[kc + k][nl]);
      ushort* dp = dst + (size_t)n * dstride + k0 + kc;
#pragma unroll
      for (int j = 0; j < 4; ++j) *(uint4*)(dp + 8 * j) = ((uint4*)buf)[j];
      __syncthreads();
    }
    return;
  }
  // b == 3755: Wvpsi fused weight + bvpsi
  WpsiS[t] = Wpsi[t];
  if (t < 16) bpsiS[t] = bpsi[t];
  for (int h2 = 0; h2 < 2; ++h2) {
    int r = t >> 1, c0 = (t & 1) * 32;
    const float* src = Wv + (size_t)r * 128 + h2 * 64 + c0;
#pragma unroll
    for (int j = 0; j < 8; ++j) {
      float4 f = *(const float4*)(src + 4 * j);
      T[r][c0 + 4 * j + 0] = f.x; T[r][c0 + 4 * j + 1] = f.y;
      T[r][c0 + 4 * j + 2] = f.z; T[r][c0 + 4 * j + 3] = f.w;
    }
    __syncthreads();
    int nl = t >> 2, kc = (t & 3) * 32;
    int n = h2 * 64 + nl;
    int hh = n >> 4, dd = n & 15;
    int lcb = hh * 16 - h2 * 64;
    ushort buf[32];
    for (int k = 0; k < 32; ++k) {
      float acc = 0.f;
#pragma unroll
      for (int dp = 0; dp < 16; ++dp)
        acc = fmaf(T[kc + k][lcb + dp], WpsiS[dp * 16 + dd], acc);
      buf[k] = f2bf(acc);
    }
    ushort* dp2 = Wts + 3 * 16384 + (size_t)n * 128 + kc;
#pragma unroll
    for (int j = 0; j < 4; ++j) *(uint4*)(dp2 + 8 * j) = ((uint4*)buf)[j];
    __syncthreads();
  }
  if (t < 128) {
    int hh = t >> 4, dd = t & 15;
    float acc = bpsiS[dd];
#pragma unroll
    for (int dp = 0; dp < 16; ++dp)
      acc = fmaf(bv[hh * 16 + dp], WpsiS[dp * 16 + dd], acc);
    bvpsi[t] = acc;
  }
}

// ---------------------------------------------------------------------------
// Kernel 2: QKV+Vpsi GEMM.  B (Wt) staged in LDS (shared across all 4 waves,
// read 8x each); A read from global (block-private rows, L2-hot).
// Epilogue through the same LDS tile -> coalesced uint4 stores.
// ---------------------------------------------------------------------------
__global__ __launch_bounds__(256) void qkv_mfma(
    const ushort* __restrict__ xb, const ushort* __restrict__ Wts,
    const float* __restrict__ bq, const float* __restrict__ bk,
    const float* __restrict__ bv, const float* __restrict__ bvpsi,
    ushort* __restrict__ qb, ushort* __restrict__ kvb) {
  __shared__ ushort Bs[128 * 136];  // 34816 B
  int t = threadIdx.x;
  int n0 = blockIdx.x * 128;
  int mat = blockIdx.y;
  const ushort* Wt = Wts + mat * 16384;
  const float* bias = (mat == 0) ? bq : (mat == 1 ? bk : (mat == 2 ? bv : bvpsi));

  // stage Wt[128][128] -> Bs stride 136, coalesced
#pragma unroll
  for (int j = 0; j < 8; ++j) {
    int idx = j * 256 + t;                 // uint4 index
    int row = idx >> 4, ko = (idx & 15) * 8;
    *(uint4*)&Bs[row * 136 + ko] = *(const uint4*)(Wt + idx * 8);
  }
  __syncthreads();

  int w = t >> 6, lane = t & 63;
  int m = lane & 15, qd = lane >> 4;
  int gr0 = n0 + w * 32;

  f32x4 acc0[8], acc1[8];
#pragma unroll
  for (int c = 0; c < 8; ++c) {
    acc0[c] = (f32x4){0.f, 0.f, 0.f, 0.f};
    acc1[c] = (f32x4){0.f, 0.f, 0.f, 0.f};
  }
#pragma unroll
  for (int kb = 0; kb < 4; ++kb) {
    int ko = kb * 32 + qd * 8;
    short8 a0 = *(const short8*)(xb + (size_t)(gr0 + m) * 128 + ko);
    short8 a1 = *(const short8*)(xb + (size_t)(gr0 + 16 + m) * 128 + ko);
#pragma unroll
    for (int c = 0; c < 8; ++c) {
      short8 bfr = *(const short8*)&Bs[(c * 16 + m) * 136 + ko];
      acc0[c] = __builtin_amdgcn_mfma_f32_16x16x32_bf16(a0, bfr, acc0[c], 0, 0, 0);
      acc1[c] = __builtin_amdgcn_mfma_f32_16x16x32_bf16(a1, bfr, acc1[c], 0, 0, 0);
    }
  }
  __syncthreads();  // all waves done reading Bs
#pragma unroll
  for (int c = 0; c < 8; ++c) {
    int col = c * 16 + m;
    float bb = bias[col];
#pragma unroll
    for (int reg = 0; reg < 4; ++reg) {
      float v0 = acc0[c][reg] + bb;
      float v1 = acc1[c][reg] + bb;
      if (mat == 3) { v0 = tanhf(v0); v1 = tanhf(v1); }
      Bs[(w * 32 + 4 * qd + reg) * 136 + col] = f2bf(v0);
      Bs[(w * 32 + 16 + 4 * qd + reg) * 136 + col] = f2bf(v1);
    }
  }
  __syncthreads();
  int row = t >> 1, half = (t & 1) * 64;
  int grow = n0 + row;
  if (grow < NN) {
    const ushort* srcl = &Bs[row * 136 + half];
    ushort* dstg = (mat == 0)
        ? qb + (size_t)grow * 128 + half
        : kvb + (size_t)grow * 384 + (mat == 1 ? 0 : (mat == 2 ? 128 : 256)) + half;
#pragma unroll
    for (int j = 0; j < 8; ++j)
      *(uint4*)(dstg + 8 * j) = *(const uint4*)(srcl + 8 * j);
  }
}

// ---------------------------------------------------------------------------
// Kernel 3: aggregate, software-pipelined.  One wave per node; lane = e*8+h
// (e = edge slot, h = head; lane owns all 16 dims of head h).
// All scol indices preloaded (16 independent loads); gather volleys double-
// buffered: FETCH(v+1) issues before CONSUME(v) -> latency overlapped.
// ---------------------------------------------------------------------------
__global__ __launch_bounds__(256) void aggregate_kernel(
    const ushort* __restrict__ qb, const ushort* __restrict__ kvb,
    const int* __restrict__ cursor, const int* __restrict__ scol,
    ushort* __restrict__ hb) {
  int wid = threadIdx.x >> 6, lane = threadIdx.x & 63;
  int node = blockIdx.x * 4 + wid;
  int e = lane >> 3, h = lane & 7;
  const float SC = 0.25f * 1.44269504f;  // 1/sqrt(D) * log2(e)

  float qv[16];
  {
    const ushort* qp = qb + (size_t)node * 128 + h * 16;
    uint4 a = *(const uint4*)qp;
    uint4 b = *(const uint4*)(qp + 8);
    uint qq[8] = {a.x, a.y, a.z, a.w, b.x, b.y, b.z, b.w};
#pragma unroll
    for (int i = 0; i < 8; ++i) {
      qv[2 * i] = bflo(qq[i]) * SC;
      qv[2 * i + 1] = bfhi(qq[i]) * SC;
    }
  }
  int cnt = cursor[node];
  cnt = cnt > 128 ? 128 : cnt;
  int base = node * 128;
  int nv = (cnt + 7) >> 3;

  int cols[16];
#pragma unroll
  for (int v = 0; v < 16; ++v) {
    int idx = v * 8 + e;
    cols[v] = scol[base + (idx < cnt ? idx : 0)];
  }

  float s = 0.f;
  float accV[16], accB[16];
#pragma unroll
  for (int j = 0; j < 16; ++j) { accV[j] = 0.f; accB[j] = 0.f; }

  uint4 rA[6], rB[6];
  auto FETCH = [&](int v, uint4* r) {
    const ushort* B = kvb + (size_t)cols[v] * 384 + h * 16;
    r[0] = *(const uint4*)(B);
    r[1] = *(const uint4*)(B + 8);
    r[2] = *(const uint4*)(B + 128);
    r[3] = *(const uint4*)(B + 136);
    r[4] = *(const uint4*)(B + 256);
    r[5] = *(const uint4*)(B + 264);
  };
  auto CONSUME = [&](int v, const uint4* r) {
    uint kk[8] = {r[0].x, r[0].y, r[0].z, r[0].w, r[1].x, r[1].y, r[1].z, r[1].w};
    uint vv[8] = {r[2].x, r[2].y, r[2].z, r[2].w, r[3].x, r[3].y, r[3].z, r[3].w};
    uint tt[8] = {r[4].x, r[4].y, r[4].z, r[4].w, r[5].x, r[5].y, r[5].z, r[5].w};
    float d = 0.f;
#pragma unroll
    for (int i = 0; i < 8; ++i) {
      d = fmaf(qv[2 * i], bflo(kk[i]), d);
      d = fmaf(qv[2 * i + 1], bfhi(kk[i]), d);
    }
    float wgt = (v * 8 + e < cnt) ? exp2f(d) : 0.f;
    s += wgt;
#pragma unroll
    for (int i = 0; i < 8; ++i) {
      accV[2 * i]     = fmaf(wgt, bflo(vv[i]), accV[2 * i]);
      accV[2 * i + 1] = fmaf(wgt, bfhi(vv[i]), accV[2 * i + 1]);
      accB[2 * i]     = fmaf(wgt, bflo(tt[i]), accB[2 * i]);
      accB[2 * i + 1] = fmaf(wgt, bfhi(tt[i]), accB[2 * i + 1]);
    }
  };

  if (nv > 0) {
    FETCH(0, rA);
    int v = 0;
    for (; v + 2 <= nv; v += 2) {
      FETCH(v + 1, rB);
      CONSUME(v, rA);
      if (v + 2 < nv) FETCH(v + 2, rA);
      CONSUME(v + 1, rB);
    }
    if (v < nv) CONSUME(v, rA);
  }

  // reduce over the 8 e-slots (lane bits 3..5)
#pragma unroll
  for (int mask = 8; mask <= 32; mask <<= 1) {
    s += __shfl_xor(s, mask);
#pragma unroll
    for (int j = 0; j < 16; ++j) {
      accV[j] += __shfl_xor(accV[j], mask);
      accB[j] += __shfl_xor(accB[j], mask);
    }
  }
  float inv = s > 0.f ? 1.f / s : 0.f;
  int dg = 2 * e;
  ushort* hp = hb + (size_t)node * 256 + h * 16 + dg;
  *(uint*)hp = (uint)f2bf(accV[dg] * inv) | ((uint)f2bf(accV[dg + 1] * inv) << 16);
  *(uint*)(hp + 128) =
      (uint)f2bf(accB[dg] * inv) | ((uint)f2bf(accB[dg + 1] * inv) << 16);
}

// ---------------------------------------------------------------------------
// Kernel 4: out = LN(x + relu(hb @ Wo + bo)) * gamma + beta.
// Wot staged in LDS (read 8x per wave); A (hb) from global; output goes
// through an LDS float tile for coalesced float4 stores.
// 313 blocks x 128 threads (2 waves x 32 rows).
// ---------------------------------------------------------------------------
__global__ __launch_bounds__(128) void output_mfma(
    const ushort* __restrict__ hb, const ushort* __restrict__ Wot,
    const float* __restrict__ x, const float* __restrict__ bo,
    const float* __restrict__ gamma, const float* __restrict__ beta,
    float* __restrict__ out) {
  __shared__ ushort Bs[128 * 264];  // 67584 B; reused as float tile
  int t = threadIdx.x;
  // stage Wot[128][256] -> Bs stride 264, coalesced
#pragma unroll
  for (int j = 0; j < 32; ++j) {
    int idx = j * 128 + t;                 // uint4 index
    int row = idx >> 5, ko = (idx & 31) * 8;
    *(uint4*)&Bs[row * 264 + ko] = *(const uint4*)(Wot + idx * 8);
  }
  __syncthreads();

  int w = t >> 6, lane = t & 63;
  int m = lane & 15, qd = lane >> 4;
  int gr0 = blockIdx.x * 64 + w * 32;

  f32x4 acc0[8], acc1[8];
#pragma unroll
  for (int c = 0; c < 8; ++c) {
    acc0[c] = (f32x4){0.f, 0.f, 0.f, 0.f};
    acc1[c] = (f32x4){0.f, 0.f, 0.f, 0.f};
  }
#pragma unroll
  for (int kb = 0; kb < 8; ++kb) {
    int ko = kb * 32 + qd * 8;
    short8 a0 = *(const short8*)(hb + (size_t)(gr0 + m) * 256 + ko);
    short8 a1 = *(const short8*)(hb + (size_t)(gr0 + 16 + m) * 256 + ko);
#pragma unroll
    for (int c = 0; c < 8; ++c) {
      short8 bfr = *(const short8*)&Bs[(c * 16 + m) * 264 + ko];
      acc0[c] = __builtin_amdgcn_mfma_f32_16x16x32_bf16(a0, bfr, acc0[c], 0, 0, 0);
      acc1[c] = __builtin_amdgcn_mfma_f32_16x16x32_bf16(a1, bfr, acc1[c], 0, 0, 0);
    }
  }
  __syncthreads();  // done reading Bs
  float* Tile = (float*)Bs;  // 64 rows x 132 floats = 33792 B
#pragma unroll
  for (int half = 0; half < 2; ++half) {
#pragma unroll
    for (int reg = 0; reg < 4; ++reg) {
      int lrow = w * 32 + half * 16 + 4 * qd + reg;
      int row = blockIdx.x * 64 + lrow;
      bool valid = row < NN;
      float vals[8];
      float sum = 0.f;
#pragma unroll
      for (int c = 0; c < 8; ++c) {
        int col = c * 16 + m;
        float a = (half ? acc1[c][reg] : acc0[c][reg]) + bo[col];
        a = fmaxf(a, 0.f);
        float xv = valid ? x[(size_t)row * 128 + col] : 0.f;
        float v = a + xv;
        vals[c] = v;
        sum += v;
      }
      sum += __shfl_xor(sum, 1); sum += __shfl_xor(sum, 2);
      sum += __shfl_xor(sum, 4); sum += __shfl_xor(sum, 8);
      float mean = sum * (1.f / 128.f);
      float ssq = 0.f;
#pragma unroll
      for (int c = 0; c < 8; ++c) {
        float d = vals[c] - mean;
        ssq = fmaf(d, d, ssq);
      }
      ssq += __shfl_xor(ssq, 1); ssq += __shfl_xor(ssq, 2);
      ssq += __shfl_xor(ssq, 4); ssq += __shfl_xor(ssq, 8);
      float rstd = rsqrtf(ssq * (1.f / 128.f) + 1e-5f);
#pragma unroll
      for (int c = 0; c < 8; ++c) {
        int col = c * 16 + m;
        Tile[lrow * 132 + col] = (vals[c] - mean) * rstd * gamma[col] + beta[col];
      }
    }
  }
  __syncthreads();
  int row = t >> 1, cb = (t & 1) * 64;
  int grow = blockIdx.x * 64 + row;
  if (grow < NN) {
    const float* srcl = &Tile[row * 132 + cb];
    float* dstg = out + (size_t)grow * 128 + cb;
#pragma unroll
    for (int j = 0; j < 16; ++j)
      *(float4*)(dstg + 4 * j) = *(const float4*)(srcl + 4 * j);
  }
}

// ---------------------------------------------------------------------------
extern "C" void kernel_launch(void* const* d_in, const int* in_sizes, int n_in,
                              void* d_out, int out_size, void* d_ws, size_t ws_size,
                              hipStream_t stream) {
  const float* x     = (const float*)d_in[0];
  const int*   ei    = (const int*)d_in[1];
  const float* Wq    = (const float*)d_in[2];
  const float* bq    = (const float*)d_in[3];
  const float* Wk    = (const float*)d_in[4];
  const float* bk    = (const float*)d_in[5];
  const float* Wv    = (const float*)d_in[6];
  const float* bv    = (const float*)d_in[7];
  const float* Wpsi  = (const float*)d_in[8];
  const float* bpsi  = (const float*)d_in[9];
  const float* Wo    = (const float*)d_in[10];
  const float* bo    = (const float*)d_in[11];
  const float* gamma = (const float*)d_in[12];
  const float* beta  = (const float*)d_in[13];
  float* out = (float*)d_out;

  char* ws = (char*)d_ws;
  ushort* xb    = (ushort*)(ws);                // 20096*128*2 = 5,144,576
  ushort* qb    = (ushort*)(ws + 5144576);      // 5,144,576
  ushort* Wts   = (ushort*)(ws + 10289152);     // 131,072
  ushort* Wot   = (ushort*)(ws + 10420224);     // 65,536
  float*  bvpsi = (float*) (ws + 10485760);     // 512
  ushort* kvb   = (ushort*)(ws + 10486272);     // 15,360,000
  ushort* hb    = (ushort*)(ws + 25846272);     // 20096*256*2 = 10,289,152
  int*    cursor= (int*)   (ws + 36135424);     // 80,000 (+pad)
  int*    scol  = (int*)   (ws + 36215552);     // 10,240,000  (~46.5 MB)

  hipMemsetAsync(cursor, 0, 80000, stream);

  prep_scatter<<<3756, 256, 0, stream>>>(x, ei, Wq, Wk, Wv, Wo, Wpsi, bpsi, bv,
                                         xb, Wts, Wot, bvpsi, cursor, scol);
  qkv_mfma<<<dim3(157, 4), 256, 0, stream>>>(xb, Wts, bq, bk, bv, bvpsi, qb, kvb);
  aggregate_kernel<<<5000, 256, 0, stream>>>(qb, kvb, cursor, scol, hb);
  output_mfma<<<313, 128, 0, stream>>>(hb, Wot, x, bo, gamma, beta, out);
}

// Round 7
// 229.309 us; speedup vs baseline: 1.0799x; 1.0565x over previous
//
#include <hip/hip_runtime.h>
#include <hip/hip_bf16.h>
#include <math.h>

#define NN 20000
#define EE 640000

typedef __attribute__((ext_vector_type(8))) short short8;
typedef __attribute__((ext_vector_type(4))) float f32x4;
typedef __hip_bfloat16 bf16;

__device__ inline ushort f2bf(float f) {
  bf16 h = __float2bfloat16(f);
  return *(ushort*)&h;
}
__device__ inline float bflo(uint u) { return __uint_as_float(u << 16); }
__device__ inline float bfhi(uint u) { return __uint_as_float(u & 0xFFFF0000u); }

// ---------------------------------------------------------------------------
// Kernel 1: edge scatter, standalone + LDS-free (max occupancy for the
// load -> atomic-return -> store latency chain).  cursor is padded to one
// counter per 64B line (stride 16 ints): same-line atomic serialization
// drops from 512/line to 32/line.  128 slots/node (Poisson(32), P>128 ~1e-30).
// ---------------------------------------------------------------------------
__global__ __launch_bounds__(256) void scatter_kernel(
    const int* __restrict__ ei, int* __restrict__ cursor,
    int* __restrict__ scol) {
  int e = blockIdx.x * 256 + threadIdx.x;
  int r = ei[e];
  int c = ei[EE + e];
  int pos = atomicAdd(&cursor[r * 16], 1);
  if (pos < 128) scol[r * 128 + pos] = c;
}

// ---------------------------------------------------------------------------
// Kernel 2: prep (conversions + weight transposes), no scatter.
//  b < 1250       : xb = bf16(x)
//  b = 1250..1252 : Wt{q,k,v}[n][k] = bf16(W[k][n])
//  b = 1253..1254 : Wot[n][256] from Wo[256][128]
//  b = 1255       : Wvpsi fused weight (psi folded into QKV GEMM) + bvpsi
// ---------------------------------------------------------------------------
__global__ __launch_bounds__(256) void prep_kernel(
    const float* __restrict__ x,
    const float* __restrict__ Wq, const float* __restrict__ Wk,
    const float* __restrict__ Wv, const float* __restrict__ Wo,
    const float* __restrict__ Wpsi, const float* __restrict__ bpsi,
    const float* __restrict__ bv,
    ushort* __restrict__ xb, ushort* __restrict__ Wts,
    ushort* __restrict__ Wot, float* __restrict__ bvpsi) {
  __shared__ float T[128][65];
  __shared__ float WpsiS[256];
  __shared__ float bpsiS[16];
  int b = blockIdx.x, t = threadIdx.x;

  if (b < 1250) {  // x -> bf16
    int idx = b * 2048 + t * 8;
    float4 f0 = *(const float4*)(x + idx);
    float4 f1 = *(const float4*)(x + idx + 4);
    ushort tmp[8] = {f2bf(f0.x), f2bf(f0.y), f2bf(f0.z), f2bf(f0.w),
                     f2bf(f1.x), f2bf(f1.y), f2bf(f1.z), f2bf(f1.w)};
    *(uint4*)(xb + idx) = *(uint4*)tmp;
    return;
  }
  if (b <= 1254) {  // weight transposes
    int which = b - 1250;
    const float* W;
    int k0 = 0, dstride;
    ushort* dst;
    if (which < 3) { W = (which == 0) ? Wq : (which == 1 ? Wk : Wv);
                     dst = Wts + which * 16384; dstride = 128; }
    else { W = Wo; k0 = (which - 3) * 128; dst = Wot; dstride = 256; }
    for (int h2 = 0; h2 < 2; ++h2) {
      int r = t >> 1, c0 = (t & 1) * 32;
      const float* src = W + (size_t)(k0 + r) * 128 + h2 * 64 + c0;
#pragma unroll
      for (int j = 0; j < 8; ++j) {
        float4 f = *(const float4*)(src + 4 * j);
        T[r][c0 + 4 * j + 0] = f.x; T[r][c0 + 4 * j + 1] = f.y;
        T[r][c0 + 4 * j + 2] = f.z; T[r][c0 + 4 * j + 3] = f.w;
      }
      __syncthreads();
      int nl = t >> 2, kc = (t & 3) * 32;
      int n = h2 * 64 + nl;
      ushort buf[32];
#pragma unroll
      for (int k = 0; k < 32; ++k) buf[k] = f2bf(T[kc + k][nl]);
      ushort* dp = dst + (size_t)n * dstride + k0 + kc;
#pragma unroll
      for (int j = 0; j < 4; ++j) *(uint4*)(dp + 8 * j) = ((uint4*)buf)[j];
      __syncthreads();
    }
    return;
  }
  // b == 1255: Wvpsi fused weight + bvpsi
  WpsiS[t] = Wpsi[t];
  if (t < 16) bpsiS[t] = bpsi[t];
  for (int h2 = 0; h2 < 2; ++h2) {
    int r = t >> 1, c0 = (t & 1) * 32;
    const float* src = Wv + (size_t)r * 128 + h2 * 64 + c0;
#pragma unroll
    for (int j = 0; j < 8; ++j) {
      float4 f = *(const float4*)(src + 4 * j);
      T[r][c0 + 4 * j + 0] = f.x; T[r][c0 + 4 * j + 1] = f.y;
      T[r][c0 + 4 * j + 2] = f.z; T[r][c0 + 4 * j + 3] = f.w;
    }
    __syncthreads();
    int nl = t >> 2, kc = (t & 3) * 32;
    int n = h2 * 64 + nl;
    int hh = n >> 4, dd = n & 15;
    int lcb = hh * 16 - h2 * 64;
    ushort buf[32];
    for (int k = 0; k < 32; ++k) {
      float acc = 0.f;
#pragma unroll
      for (int dp = 0; dp < 16; ++dp)
        acc = fmaf(T[kc + k][lcb + dp], WpsiS[dp * 16 + dd], acc);
      buf[k] = f2bf(acc);
    }
    ushort* dp2 = Wts + 3 * 16384 + (size_t)n * 128 + kc;
#pragma unroll
    for (int j = 0; j < 4; ++j) *(uint4*)(dp2 + 8 * j) = ((uint4*)buf)[j];
    __syncthreads();
  }
  if (t < 128) {
    int hh = t >> 4, dd = t & 15;
    float acc = bpsiS[dd];
#pragma unroll
    for (int dp = 0; dp < 16; ++dp)
      acc = fmaf(bv[hh * 16 + dp], WpsiS[dp * 16 + dd], acc);
    bvpsi[t] = acc;
  }
}

// ---------------------------------------------------------------------------
// Kernel 3: QKV+Vpsi GEMM.  B (Wt) staged in LDS; A from global; epilogue
// through LDS for coalesced uint4 stores.  blockIdx.y: 0:q 1:k 2:v 3:tanh.
// ---------------------------------------------------------------------------
__global__ __launch_bounds__(256) void qkv_mfma(
    const ushort* __restrict__ xb, const ushort* __restrict__ Wts,
    const float* __restrict__ bq, const float* __restrict__ bk,
    const float* __restrict__ bv, const float* __restrict__ bvpsi,
    ushort* __restrict__ qb, ushort* __restrict__ kvb) {
  __shared__ ushort Bs[128 * 136];
  int t = threadIdx.x;
  int n0 = blockIdx.x * 128;
  int mat = blockIdx.y;
  const ushort* Wt = Wts + mat * 16384;
  const float* bias = (mat == 0) ? bq : (mat == 1 ? bk : (mat == 2 ? bv : bvpsi));

#pragma unroll
  for (int j = 0; j < 8; ++j) {
    int idx = j * 256 + t;
    int row = idx >> 4, ko = (idx & 15) * 8;
    *(uint4*)&Bs[row * 136 + ko] = *(const uint4*)(Wt + idx * 8);
  }
  __syncthreads();

  int w = t >> 6, lane = t & 63;
  int m = lane & 15, qd = lane >> 4;
  int gr0 = n0 + w * 32;

  f32x4 acc0[8], acc1[8];
#pragma unroll
  for (int c = 0; c < 8; ++c) {
    acc0[c] = (f32x4){0.f, 0.f, 0.f, 0.f};
    acc1[c] = (f32x4){0.f, 0.f, 0.f, 0.f};
  }
#pragma unroll
  for (int kb = 0; kb < 4; ++kb) {
    int ko = kb * 32 + qd * 8;
    short8 a0 = *(const short8*)(xb + (size_t)(gr0 + m) * 128 + ko);
    short8 a1 = *(const short8*)(xb + (size_t)(gr0 + 16 + m) * 128 + ko);
#pragma unroll
    for (int c = 0; c < 8; ++c) {
      short8 bfr = *(const short8*)&Bs[(c * 16 + m) * 136 + ko];
      acc0[c] = __builtin_amdgcn_mfma_f32_16x16x32_bf16(a0, bfr, acc0[c], 0, 0, 0);
      acc1[c] = __builtin_amdgcn_mfma_f32_16x16x32_bf16(a1, bfr, acc1[c], 0, 0, 0);
    }
  }
  __syncthreads();
#pragma unroll
  for (int c = 0; c < 8; ++c) {
    int col = c * 16 + m;
    float bb = bias[col];
#pragma unroll
    for (int reg = 0; reg < 4; ++reg) {
      float v0 = acc0[c][reg] + bb;
      float v1 = acc1[c][reg] + bb;
      if (mat == 3) { v0 = tanhf(v0); v1 = tanhf(v1); }
      Bs[(w * 32 + 4 * qd + reg) * 136 + col] = f2bf(v0);
      Bs[(w * 32 + 16 + 4 * qd + reg) * 136 + col] = f2bf(v1);
    }
  }
  __syncthreads();
  int row = t >> 1, half = (t & 1) * 64;
  int grow = n0 + row;
  if (grow < NN) {
    const ushort* srcl = &Bs[row * 136 + half];
    ushort* dstg = (mat == 0)
        ? qb + (size_t)grow * 128 + half
        : kvb + (size_t)grow * 384 + (mat == 1 ? 0 : (mat == 2 ? 128 : 256)) + half;
#pragma unroll
    for (int j = 0; j < 8; ++j)
      *(uint4*)(dstg + 8 * j) = *(const uint4*)(srcl + 8 * j);
  }
}

// ---------------------------------------------------------------------------
// Kernel 4: aggregate, software-pipelined (R6 structure).  One wave/node;
// lane = e*8+h; cols preloaded; depth-2 double-buffered gather volleys.
// ---------------------------------------------------------------------------
__global__ __launch_bounds__(256) void aggregate_kernel(
    const ushort* __restrict__ qb, const ushort* __restrict__ kvb,
    const int* __restrict__ cursor, const int* __restrict__ scol,
    ushort* __restrict__ hb) {
  int wid = threadIdx.x >> 6, lane = threadIdx.x & 63;
  int node = blockIdx.x * 4 + wid;
  int e = lane >> 3, h = lane & 7;
  const float SC = 0.25f * 1.44269504f;

  float qv[16];
  {
    const ushort* qp = qb + (size_t)node * 128 + h * 16;
    uint4 a = *(const uint4*)qp;
    uint4 b = *(const uint4*)(qp + 8);
    uint qq[8] = {a.x, a.y, a.z, a.w, b.x, b.y, b.z, b.w};
#pragma unroll
    for (int i = 0; i < 8; ++i) {
      qv[2 * i] = bflo(qq[i]) * SC;
      qv[2 * i + 1] = bfhi(qq[i]) * SC;
    }
  }
  int cnt = cursor[node * 16];
  cnt = cnt > 128 ? 128 : cnt;
  int base = node * 128;
  int nv = (cnt + 7) >> 3;

  int cols[16];
#pragma unroll
  for (int v = 0; v < 16; ++v) {
    int idx = v * 8 + e;
    cols[v] = scol[base + (idx < cnt ? idx : 0)];
  }

  float s = 0.f;
  float accV[16], accB[16];
#pragma unroll
  for (int j = 0; j < 16; ++j) { accV[j] = 0.f; accB[j] = 0.f; }

  uint4 rA[6], rB[6];
  auto FETCH = [&](int v, uint4* r) {
    const ushort* B = kvb + (size_t)cols[v] * 384 + h * 16;
    r[0] = *(const uint4*)(B);
    r[1] = *(const uint4*)(B + 8);
    r[2] = *(const uint4*)(B + 128);
    r[3] = *(const uint4*)(B + 136);
    r[4] = *(const uint4*)(B + 256);
    r[5] = *(const uint4*)(B + 264);
  };
  auto CONSUME = [&](int v, const uint4* r) {
    uint kk[8] = {r[0].x, r[0].y, r[0].z, r[0].w, r[1].x, r[1].y, r[1].z, r[1].w};
    uint vv[8] = {r[2].x, r[2].y, r[2].z, r[2].w, r[3].x, r[3].y, r[3].z, r[3].w};
    uint tt[8] = {r[4].x, r[4].y, r[4].z, r[4].w, r[5].x, r[5].y, r[5].z, r[5].w};
    float d = 0.f;
#pragma unroll
    for (int i = 0; i < 8; ++i) {
      d = fmaf(qv[2 * i], bflo(kk[i]), d);
      d = fmaf(qv[2 * i + 1], bfhi(kk[i]), d);
    }
    float wgt = (v * 8 + e < cnt) ? exp2f(d) : 0.f;
    s += wgt;
#pragma unroll
    for (int i = 0; i < 8; ++i) {
      accV[2 * i]     = fmaf(wgt, bflo(vv[i]), accV[2 * i]);
      accV[2 * i + 1] = fmaf(wgt, bfhi(vv[i]), accV[2 * i + 1]);
      accB[2 * i]     = fmaf(wgt, bflo(tt[i]), accB[2 * i]);
      accB[2 * i + 1] = fmaf(wgt, bfhi(tt[i]), accB[2 * i + 1]);
    }
  };

  if (nv > 0) {
    FETCH(0, rA);
    int v = 0;
    for (; v + 2 <= nv; v += 2) {
      FETCH(v + 1, rB);
      CONSUME(v, rA);
      if (v + 2 < nv) FETCH(v + 2, rA);
      CONSUME(v + 1, rB);
    }
    if (v < nv) CONSUME(v, rA);
  }

#pragma unroll
  for (int mask = 8; mask <= 32; mask <<= 1) {
    s += __shfl_xor(s, mask);
#pragma unroll
    for (int j = 0; j < 16; ++j) {
      accV[j] += __shfl_xor(accV[j], mask);
      accB[j] += __shfl_xor(accB[j], mask);
    }
  }
  float inv = s > 0.f ? 1.f / s : 0.f;
  int dg = 2 * e;
  ushort* hp = hb + (size_t)node * 256 + h * 16 + dg;
  *(uint*)hp = (uint)f2bf(accV[dg] * inv) | ((uint)f2bf(accV[dg + 1] * inv) << 16);
  *(uint*)(hp + 128) =
      (uint)f2bf(accB[dg] * inv) | ((uint)f2bf(accB[dg + 1] * inv) << 16);
}

// ---------------------------------------------------------------------------
// Kernel 5: out = LN(x + relu(hb @ Wo + bo)) * gamma + beta.  Wot in LDS,
// A from global, output through LDS float tile (coalesced float4 stores).
// ---------------------------------------------------------------------------
__global__ __launch_bounds__(128) void output_mfma(
    const ushort* __restrict__ hb, const ushort* __restrict__ Wot,
    const float* __restrict__ x, const float* __restrict__ bo,
    const float* __restrict__ gamma, const float* __restrict__ beta,
    float* __restrict__ out) {
  __shared__ ushort Bs[128 * 264];
  int t = threadIdx.x;
#pragma unroll
  for (int j = 0; j < 32; ++j) {
    int idx = j * 128 + t;
    int row = idx >> 5, ko = (idx & 31) * 8;
    *(uint4*)&Bs[row * 264 + ko] = *(const uint4*)(Wot + idx * 8);
  }
  __syncthreads();

  int w = t >> 6, lane = t & 63;
  int m = lane & 15, qd = lane >> 4;
  int gr0 = blockIdx.x * 64 + w * 32;

  f32x4 acc0[8], acc1[8];
#pragma unroll
  for (int c = 0; c < 8; ++c) {
    acc0[c] = (f32x4){0.f, 0.f, 0.f, 0.f};
    acc1[c] = (f32x4){0.f, 0.f, 0.f, 0.f};
  }
#pragma unroll
  for (int kb = 0; kb < 8; ++kb) {
    int ko = kb * 32 + qd * 8;
    short8 a0 = *(const short8*)(hb + (size_t)(gr0 + m) * 256 + ko);
    short8 a1 = *(const short8*)(hb + (size_t)(gr0 + 16 + m) * 256 + ko);
#pragma unroll
    for (int c = 0; c < 8; ++c) {
      short8 bfr = *(const short8*)&Bs[(c * 16 + m) * 264 + ko];
      acc0[c] = __builtin_amdgcn_mfma_f32_16x16x32_bf16(a0, bfr, acc0[c], 0, 0, 0);
      acc1[c] = __builtin_amdgcn_mfma_f32_16x16x32_bf16(a1, bfr, acc1[c], 0, 0, 0);
    }
  }
  __syncthreads();
  float* Tile = (float*)Bs;
#pragma unroll
  for (int half = 0; half < 2; ++half) {
#pragma unroll
    for (int reg = 0; reg < 4; ++reg) {
      int lrow = w * 32 + half * 16 + 4 * qd + reg;
      int row = blockIdx.x * 64 + lrow;
      bool valid = row < NN;
      float vals[8];
      float sum = 0.f;
#pragma unroll
      for (int c = 0; c < 8; ++c) {
        int col = c * 16 + m;
        float a = (half ? acc1[c][reg] : acc0[c][reg]) + bo[col];
        a = fmaxf(a, 0.f);
        float xv = valid ? x[(size_t)row * 128 + col] : 0.f;
        float v = a + xv;
        vals[c] = v;
        sum += v;
      }
      sum += __shfl_xor(sum, 1); sum += __shfl_xor(sum, 2);
      sum += __shfl_xor(sum, 4); sum += __shfl_xor(sum, 8);
      float mean = sum * (1.f / 128.f);
      float ssq = 0.f;
#pragma unroll
      for (int c = 0; c < 8; ++c) {
        float d = vals[c] - mean;
        ssq = fmaf(d, d, ssq);
      }
      ssq += __shfl_xor(ssq, 1); ssq += __shfl_xor(ssq, 2);
      ssq += __shfl_xor(ssq, 4); ssq += __shfl_xor(ssq, 8);
      float rstd = rsqrtf(ssq * (1.f / 128.f) + 1e-5f);
#pragma unroll
      for (int c = 0; c < 8; ++c) {
        int col = c * 16 + m;
        Tile[lrow * 132 + col] = (vals[c] - mean) * rstd * gamma[col] + beta[col];
      }
    }
  }
  __syncthreads();
  int row = t >> 1, cb = (t & 1) * 64;
  int grow = blockIdx.x * 64 + row;
  if (grow < NN) {
    const float* srcl = &Tile[row * 132 + cb];
    float* dstg = out + (size_t)grow * 128 + cb;
#pragma unroll
    for (int j = 0; j < 16; ++j)
      *(float4*)(dstg + 4 * j) = *(const float4*)(srcl + 4 * j);
  }
}

// ---------------------------------------------------------------------------
extern "C" void kernel_launch(void* const* d_in, const int* in_sizes, int n_in,
                              void* d_out, int out_size, void* d_ws, size_t ws_size,
                              hipStream_t stream) {
  const float* x     = (const float*)d_in[0];
  const int*   ei    = (const int*)d_in[1];
  const float* Wq    = (const float*)d_in[2];
  const float* bq    = (const float*)d_in[3];
  const float* Wk    = (const float*)d_in[4];
  const float* bk    = (const float*)d_in[5];
  const float* Wv    = (const float*)d_in[6];
  const float* bv    = (const float*)d_in[7];
  const float* Wpsi  = (const float*)d_in[8];
  const float* bpsi  = (const float*)d_in[9];
  const float* Wo    = (const float*)d_in[10];
  const float* bo    = (const float*)d_in[11];
  const float* gamma = (const float*)d_in[12];
  const float* beta  = (const float*)d_in[13];
  float* out = (float*)d_out;

  char* ws = (char*)d_ws;
  ushort* xb    = (ushort*)(ws);                // 5,144,576
  ushort* qb    = (ushort*)(ws + 5144576);      // 5,144,576
  ushort* Wts   = (ushort*)(ws + 10289152);     // 131,072
  ushort* Wot   = (ushort*)(ws + 10420224);     // 65,536
  float*  bvpsi = (float*) (ws + 10485760);     // 512
  ushort* kvb   = (ushort*)(ws + 10486272);     // 15,360,000
  ushort* hb    = (ushort*)(ws + 25846272);     // 10,289,152
  int*    cursor= (int*)   (ws + 36135424);     // 20000*64 = 1,280,000
  int*    scol  = (int*)   (ws + 37415424);     // 10,240,000  (~47.7 MB)

  hipMemsetAsync(cursor, 0, 1280000, stream);

  scatter_kernel<<<2500, 256, 0, stream>>>(ei, cursor, scol);
  prep_kernel<<<1256, 256, 0, stream>>>(x, Wq, Wk, Wv, Wo, Wpsi, bpsi, bv,
                                        xb, Wts, Wot, bvpsi);
  qkv_mfma<<<dim3(157, 4), 256, 0, stream>>>(xb, Wts, bq, bk, bv, bvpsi, qb, kvb);
  aggregate_kernel<<<5000, 256, 0, stream>>>(qb, kvb, cursor, scol, hb);
  output_mfma<<<313, 128, 0, stream>>>(hb, Wot, x, bo, gamma, beta, out);
}